// Round 1
// baseline (275.061 us; speedup 1.0000x reference)
//
#include <hip/hip_runtime.h>
#include <hip/hip_bf16.h>

// ---------------------------------------------------------------------------
// Qwen2.5 vision attention block, MI355X bf16-MFMA implementation.
// T=2304, HIDDEN=1280, NH=16, HD=80, WINDOW=64 (36 full windows, no padding).
// Stage 1: qkv = x @ Wqkv + bqkv             (bf16 MFMA, out bf16 -> ws)
// Stage 2: per (window, head): rotary + softmax(QK^T/sqrt(80))V  (MFMA)
// Stage 3: out = attn @ Wo + bo              (bf16 MFMA, out fp32)
// ---------------------------------------------------------------------------

typedef __bf16 bf16x8 __attribute__((ext_vector_type(8)));
typedef float  f32x4  __attribute__((ext_vector_type(4)));

#define T_TOK   2304
#define HID     1280
#define QKV_N   3840
#define NH      16
#define HD      80
#define WIN     64
#define NWIN    36

// ---------------------------------------------------------------------------
// GEMM: C[M,N] = A[M,K] @ B[K,N] (+bias). A fp32, B fp32, out bf16.
// Tile 64x64x32, 4 waves, one 16x16x32 MFMA per (wave-row, col-tile, k-step).
// ---------------------------------------------------------------------------
__global__ __launch_bounds__(256) void gemm_qkv_kernel(
    const float* __restrict__ X,     // [2304,1280]
    const float* __restrict__ W,     // [1280,3840]
    const float* __restrict__ bias,  // [3840]
    __bf16* __restrict__ out)        // [2304,3840] bf16
{
    const int n0 = blockIdx.x * 64;   // 60 tiles
    const int m0 = blockIdx.y * 64;   // 36 tiles

    __shared__ __bf16 As[64 * 40];    // [m][k] stride 40
    __shared__ __bf16 Bs[64 * 40];    // [n][k] stride 40 (transposed)

    const int tid  = threadIdx.x;
    const int wave = tid >> 6;
    const int lane = tid & 63;
    const int quad = lane >> 4;
    const int l16  = lane & 15;

    // staging indices
    const int ar = tid >> 2;          // 0..63 (A row)
    const int ac = (tid & 3) * 8;     // A col group (8 floats)
    const int bk = tid >> 3;          // 0..31 (B k row)
    const int bn = (tid & 7) * 8;     // B n group (8 floats)

    f32x4 acc[4] = {};

    for (int k0 = 0; k0 < 1280; k0 += 32) {
        // global loads (fp32)
        const float4* ap = (const float4*)(X + (size_t)(m0 + ar) * 1280 + k0 + ac);
        float4 a0 = ap[0], a1 = ap[1];
        const float4* bp = (const float4*)(W + (size_t)(k0 + bk) * QKV_N + n0 + bn);
        float4 b0 = bp[0], b1 = bp[1];

        __syncthreads();   // protect previous iteration's LDS reads

        __bf16* ad = As + ar * 40 + ac;
        ad[0] = (__bf16)a0.x; ad[1] = (__bf16)a0.y; ad[2] = (__bf16)a0.z; ad[3] = (__bf16)a0.w;
        ad[4] = (__bf16)a1.x; ad[5] = (__bf16)a1.y; ad[6] = (__bf16)a1.z; ad[7] = (__bf16)a1.w;

        Bs[(bn + 0) * 40 + bk] = (__bf16)b0.x;
        Bs[(bn + 1) * 40 + bk] = (__bf16)b0.y;
        Bs[(bn + 2) * 40 + bk] = (__bf16)b0.z;
        Bs[(bn + 3) * 40 + bk] = (__bf16)b0.w;
        Bs[(bn + 4) * 40 + bk] = (__bf16)b1.x;
        Bs[(bn + 5) * 40 + bk] = (__bf16)b1.y;
        Bs[(bn + 6) * 40 + bk] = (__bf16)b1.z;
        Bs[(bn + 7) * 40 + bk] = (__bf16)b1.w;

        __syncthreads();

        bf16x8 af = *(const bf16x8*)(As + (wave * 16 + l16) * 40 + quad * 8);
#pragma unroll
        for (int ct = 0; ct < 4; ++ct) {
            bf16x8 bf = *(const bf16x8*)(Bs + (ct * 16 + l16) * 40 + quad * 8);
            acc[ct] = __builtin_amdgcn_mfma_f32_16x16x32_bf16(af, bf, acc[ct], 0, 0, 0);
        }
    }

#pragma unroll
    for (int ct = 0; ct < 4; ++ct) {
        const int col = n0 + ct * 16 + l16;
        const float b = bias[col];
#pragma unroll
        for (int r = 0; r < 4; ++r) {
            const int row = m0 + wave * 16 + quad * 4 + r;
            out[(size_t)row * QKV_N + col] = (__bf16)(acc[ct][r] + b);
        }
    }
}

// ---------------------------------------------------------------------------
// Output GEMM: out[M,N] = attn[M,K](bf16) @ Wo[K,N](fp32) + bo, out fp32.
// ---------------------------------------------------------------------------
__global__ __launch_bounds__(256) void gemm_out_kernel(
    const __bf16* __restrict__ Abf,  // [2304,1280] bf16
    const float* __restrict__ W,     // [1280,1280]
    const float* __restrict__ bias,  // [1280]
    float* __restrict__ out)         // [2304,1280] fp32
{
    const int n0 = blockIdx.x * 64;   // 20 tiles
    const int m0 = blockIdx.y * 64;   // 36 tiles

    __shared__ __bf16 As[64 * 40];
    __shared__ __bf16 Bs[64 * 40];

    const int tid  = threadIdx.x;
    const int wave = tid >> 6;
    const int lane = tid & 63;
    const int quad = lane >> 4;
    const int l16  = lane & 15;

    const int ar = tid >> 2;
    const int ac = (tid & 3) * 8;
    const int bk = tid >> 3;
    const int bn = (tid & 7) * 8;

    f32x4 acc[4] = {};

    for (int k0 = 0; k0 < 1280; k0 += 32) {
        bf16x8 a8 = *(const bf16x8*)(Abf + (size_t)(m0 + ar) * HID + k0 + ac);
        const float4* bp = (const float4*)(W + (size_t)(k0 + bk) * HID + n0 + bn);
        float4 b0 = bp[0], b1 = bp[1];

        __syncthreads();

        *(bf16x8*)(As + ar * 40 + ac) = a8;

        Bs[(bn + 0) * 40 + bk] = (__bf16)b0.x;
        Bs[(bn + 1) * 40 + bk] = (__bf16)b0.y;
        Bs[(bn + 2) * 40 + bk] = (__bf16)b0.z;
        Bs[(bn + 3) * 40 + bk] = (__bf16)b0.w;
        Bs[(bn + 4) * 40 + bk] = (__bf16)b1.x;
        Bs[(bn + 5) * 40 + bk] = (__bf16)b1.y;
        Bs[(bn + 6) * 40 + bk] = (__bf16)b1.z;
        Bs[(bn + 7) * 40 + bk] = (__bf16)b1.w;

        __syncthreads();

        bf16x8 af = *(const bf16x8*)(As + (wave * 16 + l16) * 40 + quad * 8);
#pragma unroll
        for (int ct = 0; ct < 4; ++ct) {
            bf16x8 bf = *(const bf16x8*)(Bs + (ct * 16 + l16) * 40 + quad * 8);
            acc[ct] = __builtin_amdgcn_mfma_f32_16x16x32_bf16(af, bf, acc[ct], 0, 0, 0);
        }
    }

#pragma unroll
    for (int ct = 0; ct < 4; ++ct) {
        const int col = n0 + ct * 16 + l16;
        const float b = bias[col];
#pragma unroll
        for (int r = 0; r < 4; ++r) {
            const int row = m0 + wave * 16 + quad * 4 + r;
            out[(size_t)row * HID + col] = acc[ct][r] + b;
        }
    }
}

// ---------------------------------------------------------------------------
// Fused rotary + windowed attention. One block per (window, head).
// Windows are exactly 64 full tokens -> no mask, plain softmax over 64 keys.
// Q/K: rotary applied on load (fp32 math), bf16 to LDS, K-dim padded 80->96.
// S = Q K^T via MFMA; softmax in LDS (fp32); P bf16; O = P V via MFMA.
// ---------------------------------------------------------------------------
__global__ __launch_bounds__(256) void attn_win_kernel(
    const __bf16* __restrict__ qkv,   // [2304, 3840] bf16
    const float* __restrict__ rope,   // [2304, 40]
    __bf16* __restrict__ attn_out)    // [2304, 1280] bf16
{
    const int w = blockIdx.x;   // window 0..35
    const int h = blockIdx.y;   // head   0..15

    __shared__ __bf16 Qs[64 * 104];  // [t][d], d padded to 96, stride 104
    __shared__ __bf16 Ks[64 * 104];  // [t][d]  (== B-operand layout for QK^T)
    __shared__ __bf16 Vt[80 * 72];   // [d][t], stride 72
    __shared__ float  Ss[64 * 68];   // scores, stride 68
    __shared__ __bf16 Ps[64 * 72];   // probs,  stride 72

    const int tid = threadIdx.x;

    // ---- load + rotary ----
    for (int idx = tid; idx < 64 * 80; idx += 256) {
        const int t = idx / 80, d = idx % 80;
        const int tg = w * 64 + t;
        const size_t base = (size_t)tg * QKV_N + h * HD;
        const float q = (float)qkv[base + d];
        const float k = (float)qkv[base + HID + d];
        const float v = (float)qkv[base + 2 * HID + d];
        const int dr = (d < 40) ? d : d - 40;
        const int dp = (d < 40) ? d + 40 : d - 40;
        const float ang = rope[tg * 40 + dr];
        const float c = __cosf(ang), s = __sinf(ang);
        const float qp = (float)qkv[base + dp];
        const float kp = (float)qkv[base + HID + dp];
        const float qr = (d < 40) ? (q * c - qp * s) : (qp * s + q * c);
        const float kr = (d < 40) ? (k * c - kp * s) : (kp * s + k * c);
        Qs[t * 104 + d] = (__bf16)qr;
        Ks[t * 104 + d] = (__bf16)kr;
        Vt[d * 72 + t] = (__bf16)v;
    }
    // zero-pad d in [80,96)
    for (int idx = tid; idx < 64 * 16; idx += 256) {
        const int t = idx >> 4, d = 80 + (idx & 15);
        Qs[t * 104 + d] = (__bf16)0.f;
        Ks[t * 104 + d] = (__bf16)0.f;
    }
    __syncthreads();

    const int wave = tid >> 6, lane = tid & 63;
    const int quad = lane >> 4, l16 = lane & 15;

    // ---- S = Q K^T ----
    f32x4 sacc[4] = {};
#pragma unroll
    for (int k0 = 0; k0 < 96; k0 += 32) {
        bf16x8 af = *(const bf16x8*)(Qs + (wave * 16 + l16) * 104 + k0 + quad * 8);
#pragma unroll
        for (int ct = 0; ct < 4; ++ct) {
            bf16x8 bf = *(const bf16x8*)(Ks + (ct * 16 + l16) * 104 + k0 + quad * 8);
            sacc[ct] = __builtin_amdgcn_mfma_f32_16x16x32_bf16(af, bf, sacc[ct], 0, 0, 0);
        }
    }
    const float scale = 0.11180339887498948f;  // 1/sqrt(80)
#pragma unroll
    for (int ct = 0; ct < 4; ++ct)
#pragma unroll
        for (int r = 0; r < 4; ++r)
            Ss[(wave * 16 + quad * 4 + r) * 68 + ct * 16 + l16] = sacc[ct][r] * scale;
    __syncthreads();

    // ---- softmax: 4 lanes per row, 16 cols each ----
    {
        const int row = tid >> 2, part = tid & 3;
        float vals[16];
        float mx = -1e30f;
#pragma unroll
        for (int j = 0; j < 16; ++j) {
            vals[j] = Ss[row * 68 + part * 16 + j];
            mx = fmaxf(mx, vals[j]);
        }
        mx = fmaxf(mx, __shfl_xor(mx, 1));
        mx = fmaxf(mx, __shfl_xor(mx, 2));
        float sum = 0.f;
#pragma unroll
        for (int j = 0; j < 16; ++j) {
            vals[j] = __expf(vals[j] - mx);
            sum += vals[j];
        }
        sum += __shfl_xor(sum, 1);
        sum += __shfl_xor(sum, 2);
        const float inv = 1.0f / sum;
#pragma unroll
        for (int j = 0; j < 16; ++j)
            Ps[row * 72 + part * 16 + j] = (__bf16)(vals[j] * inv);
    }
    __syncthreads();

    // ---- O = P V : 16 rows/wave x 80 cols (5 n-tiles) ----
    f32x4 oacc[5] = {};
#pragma unroll
    for (int k0 = 0; k0 < 64; k0 += 32) {
        bf16x8 af = *(const bf16x8*)(Ps + (wave * 16 + l16) * 72 + k0 + quad * 8);
#pragma unroll
        for (int nt = 0; nt < 5; ++nt) {
            bf16x8 bf = *(const bf16x8*)(Vt + (nt * 16 + l16) * 72 + k0 + quad * 8);
            oacc[nt] = __builtin_amdgcn_mfma_f32_16x16x32_bf16(af, bf, oacc[nt], 0, 0, 0);
        }
    }
#pragma unroll
    for (int nt = 0; nt < 5; ++nt) {
        const int d = nt * 16 + l16;
#pragma unroll
        for (int r = 0; r < 4; ++r) {
            const int t = w * 64 + wave * 16 + quad * 4 + r;
            attn_out[(size_t)t * HID + h * HD + d] = (__bf16)oacc[nt][r];
        }
    }
}

// ---------------------------------------------------------------------------
extern "C" void kernel_launch(void* const* d_in, const int* in_sizes, int n_in,
                              void* d_out, int out_size, void* d_ws, size_t ws_size,
                              hipStream_t stream) {
    const float* x    = (const float*)d_in[0];  // [2304,1,1280]
    const float* rope = (const float*)d_in[1];  // [2304,40]
    // d_in[2] = cu_window_seqlens (structure known statically: 64-token windows)
    const float* Wqkv = (const float*)d_in[3];  // [1280,3840]
    const float* bqkv = (const float*)d_in[4];  // [3840]
    const float* Wo   = (const float*)d_in[5];  // [1280,1280]
    const float* bo   = (const float*)d_in[6];  // [1280]
    float* out = (float*)d_out;

    __bf16* qkv_bf  = (__bf16*)d_ws;                                       // 2304*3840*2 B
    __bf16* attn_bf = (__bf16*)((char*)d_ws + (size_t)T_TOK * QKV_N * 2);  // 2304*1280*2 B

    gemm_qkv_kernel<<<dim3(QKV_N / 64, T_TOK / 64), 256, 0, stream>>>(x, Wqkv, bqkv, qkv_bf);
    attn_win_kernel<<<dim3(NWIN, NH), 256, 0, stream>>>(qkv_bf, rope, attn_bf);
    gemm_out_kernel<<<dim3(HID / 64, T_TOK / 64), 256, 0, stream>>>(attn_bf, Wo, bo, out);
}

// Round 2
// 172.084 us; speedup vs baseline: 1.5984x; 1.5984x over previous
//
#include <hip/hip_runtime.h>
#include <hip/hip_bf16.h>

typedef __bf16 bf16x8 __attribute__((ext_vector_type(8)));
typedef __bf16 bf16x4v __attribute__((ext_vector_type(4)));
typedef float  f32x4  __attribute__((ext_vector_type(4)));

#define T_TOK   2304
#define HID     1280
#define QKV_N   3840
#define NH      16
#define HD      80
#define NWIN    36

// ---------------------------------------------------------------------------
// async global->LDS 16B copy (wave-uniform LDS base + lane*16 semantics)
// ---------------------------------------------------------------------------
__device__ inline void async_copy16(const __bf16* g, __bf16* l) {
    __builtin_amdgcn_global_load_lds(
        (const __attribute__((address_space(1))) unsigned int*)g,
        (__attribute__((address_space(3))) unsigned int*)l, 16, 0, 0);
}

// ---------------------------------------------------------------------------
// x fp32 -> bf16 (elementwise, 8/thread)
// ---------------------------------------------------------------------------
__global__ __launch_bounds__(256) void convert_bf16_kernel(
    const float* __restrict__ in, __bf16* __restrict__ out)
{
    const int i = (blockIdx.x * 256 + threadIdx.x) * 8;
    const float4* p = (const float4*)(in + i);
    float4 a = p[0], b = p[1];
    bf16x8 o;
    o[0] = (__bf16)a.x; o[1] = (__bf16)a.y; o[2] = (__bf16)a.z; o[3] = (__bf16)a.w;
    o[4] = (__bf16)b.x; o[5] = (__bf16)b.y; o[6] = (__bf16)b.z; o[7] = (__bf16)b.w;
    *(bf16x8*)(out + i) = o;
}

// ---------------------------------------------------------------------------
// W fp32 [R][C] -> W^T bf16 [C][R].  64x64 tiles via LDS.
// ---------------------------------------------------------------------------
__global__ __launch_bounds__(256) void transpose_bf16_kernel(
    const float* __restrict__ in, __bf16* __restrict__ outT, int R, int C)
{
    __shared__ float t[64][65];
    const int c0 = blockIdx.x * 64;
    const int r0 = blockIdx.y * 64;
    const int tid = threadIdx.x;
    const int lr = tid >> 4;           // 0..15
    const int lc = (tid & 15) * 4;     // 0..60
#pragma unroll
    for (int i = 0; i < 4; ++i) {
        float4 v = *(const float4*)(in + (size_t)(r0 + lr + i * 16) * C + c0 + lc);
        float* d = &t[lr + i * 16][lc];
        d[0] = v.x; d[1] = v.y; d[2] = v.z; d[3] = v.w;
    }
    __syncthreads();
    const int oc  = tid >> 4;          // in-col (out-row) 0..15 (+16i)
    const int orr = (tid & 15) * 4;    // in-row (out-col)
#pragma unroll
    for (int i = 0; i < 4; ++i) {
        const int c = oc + i * 16;
        bf16x4v o;
        o[0] = (__bf16)t[orr + 0][c];
        o[1] = (__bf16)t[orr + 1][c];
        o[2] = (__bf16)t[orr + 2][c];
        o[3] = (__bf16)t[orr + 3][c];
        *(bf16x4v*)(outT + (size_t)(c0 + c) * R + r0 + orr) = o;
    }
}

// ---------------------------------------------------------------------------
// m97-style GEMM: out[M,N] = A[M,K=1280](bf16) @ Bt[N,K=1280](bf16)^T + bias.
// 128x128 tile, BK=32, global_load_lds 16B staging, 4 waves (2x2), each wave
// 64x64 = 4x4 grid of 16x16x32 MFMAs.
// ---------------------------------------------------------------------------
template<typename OutT>
__global__ __launch_bounds__(256) void gemm_bt_kernel(
    const __bf16* __restrict__ A,    // [M,1280]
    const __bf16* __restrict__ Bt,   // [N,1280]
    const float* __restrict__ bias,  // [N]
    OutT* __restrict__ out,          // [M,N]
    int N)
{
    const int n0 = blockIdx.x * 128;
    const int m0 = blockIdx.y * 128;

    __shared__ __align__(16) __bf16 As[128 * 32];
    __shared__ __align__(16) __bf16 Bs[128 * 32];

    const int tid  = threadIdx.x;
    const int wave = tid >> 6;
    const int lane = tid & 63;
    const int quad = lane >> 4;
    const int l16  = lane & 15;
    const int wm   = (wave >> 1) * 64;
    const int wn   = (wave & 1) * 64;

    // staging: lane covers row (lane>>2), k-octet (lane&3)*8 within a 16-row slab
    const int srow = lane >> 2;
    const int scol = (lane & 3) * 8;

    f32x4 acc[4][4] = {};

    for (int k0 = 0; k0 < 1280; k0 += 32) {
        __syncthreads();   // previous iteration's LDS reads complete
#pragma unroll
        for (int i = 0; i < 2; ++i) {
            const int r = wave * 32 + i * 16 + srow;   // 0..127
            async_copy16(A  + (size_t)(m0 + r) * 1280 + k0 + scol, As + r * 32 + scol);
            async_copy16(Bt + (size_t)(n0 + r) * 1280 + k0 + scol, Bs + r * 32 + scol);
        }
        __syncthreads();   // vmcnt(0) drained before barrier -> LDS ready

        bf16x8 af[4], bf[4];
#pragma unroll
        for (int i = 0; i < 4; ++i) {
            af[i] = *(const bf16x8*)(As + (wm + i * 16 + l16) * 32 + quad * 8);
            bf[i] = *(const bf16x8*)(Bs + (wn + i * 16 + l16) * 32 + quad * 8);
        }
#pragma unroll
        for (int mt = 0; mt < 4; ++mt)
#pragma unroll
            for (int nt = 0; nt < 4; ++nt)
                acc[mt][nt] = __builtin_amdgcn_mfma_f32_16x16x32_bf16(
                    af[mt], bf[nt], acc[mt][nt], 0, 0, 0);
    }

#pragma unroll
    for (int nt = 0; nt < 4; ++nt) {
        const int col = n0 + wn + nt * 16 + l16;
        const float b = bias[col];
#pragma unroll
        for (int mt = 0; mt < 4; ++mt) {
#pragma unroll
            for (int r = 0; r < 4; ++r) {
                const int row = m0 + wm + mt * 16 + quad * 4 + r;
                out[(size_t)row * N + col] = (OutT)(acc[mt][nt][r] + b);
            }
        }
    }
}

// ---------------------------------------------------------------------------
// Fused rotary + windowed attention. One block per (window, head).
// 36 full 64-token windows -> dense 64x64 softmax blocks, no masking.
// ---------------------------------------------------------------------------
__global__ __launch_bounds__(256) void attn_win_kernel(
    const __bf16* __restrict__ qkv,   // [2304, 3840]
    const float* __restrict__ rope,   // [2304, 40]
    __bf16* __restrict__ attn_out)    // [2304, 1280]
{
    const int w = blockIdx.x;
    const int h = blockIdx.y;

    __shared__ __bf16 Qs[64 * 104];  // [t][d], d padded 80->96, stride 104
    __shared__ __bf16 Ks[64 * 104];
    __shared__ __bf16 Vt[80 * 72];   // [d][t], stride 72
    __shared__ __bf16 Ps[64 * 72];   // probs, stride 72

    const int tid = threadIdx.x;

    // ---- load + rotary (each element touched once; one sincos per pair) ----
    for (int idx = tid; idx < 64 * 40; idx += 256) {
        const int t = idx / 40, d = idx - t * 40;
        const int tg = w * 64 + t;
        const size_t base = (size_t)tg * QKV_N + h * HD;
        const float q0 = (float)qkv[base + d],            q1 = (float)qkv[base + d + 40];
        const float k0 = (float)qkv[base + HID + d],      k1 = (float)qkv[base + HID + d + 40];
        const float v0 = (float)qkv[base + 2 * HID + d],  v1 = (float)qkv[base + 2 * HID + d + 40];
        float sn, cs;
        __sincosf(rope[tg * 40 + d], &sn, &cs);
        Qs[t * 104 + d]      = (__bf16)(q0 * cs - q1 * sn);
        Qs[t * 104 + d + 40] = (__bf16)(q0 * sn + q1 * cs);
        Ks[t * 104 + d]      = (__bf16)(k0 * cs - k1 * sn);
        Ks[t * 104 + d + 40] = (__bf16)(k0 * sn + k1 * cs);
        Vt[d * 72 + t]        = (__bf16)v0;
        Vt[(d + 40) * 72 + t] = (__bf16)v1;
    }
    for (int idx = tid; idx < 64 * 16; idx += 256) {
        const int t = idx >> 4, d = 80 + (idx & 15);
        Qs[t * 104 + d] = (__bf16)0.f;
        Ks[t * 104 + d] = (__bf16)0.f;
    }
    __syncthreads();

    const int wave = tid >> 6, lane = tid & 63;
    const int quad = lane >> 4, l16 = lane & 15;

    // ---- S = Q K^T ----
    f32x4 sacc[4] = {};
#pragma unroll
    for (int k0 = 0; k0 < 96; k0 += 32) {
        bf16x8 af = *(const bf16x8*)(Qs + (wave * 16 + l16) * 104 + k0 + quad * 8);
#pragma unroll
        for (int ct = 0; ct < 4; ++ct) {
            bf16x8 bf = *(const bf16x8*)(Ks + (ct * 16 + l16) * 104 + k0 + quad * 8);
            sacc[ct] = __builtin_amdgcn_mfma_f32_16x16x32_bf16(af, bf, sacc[ct], 0, 0, 0);
        }
    }

    // ---- in-register softmax (row = wave*16+quad*4+r, cols over l16 x ct) ----
    const float scale = 0.11180339887498948f;  // 1/sqrt(80)
#pragma unroll
    for (int r = 0; r < 4; ++r) {
        float m = -1e30f;
#pragma unroll
        for (int ct = 0; ct < 4; ++ct) {
            sacc[ct][r] *= scale;
            m = fmaxf(m, sacc[ct][r]);
        }
        m = fmaxf(m, __shfl_xor(m, 1));
        m = fmaxf(m, __shfl_xor(m, 2));
        m = fmaxf(m, __shfl_xor(m, 4));
        m = fmaxf(m, __shfl_xor(m, 8));
        float e[4], s = 0.f;
#pragma unroll
        for (int ct = 0; ct < 4; ++ct) {
            e[ct] = __expf(sacc[ct][r] - m);
            s += e[ct];
        }
        s += __shfl_xor(s, 1);
        s += __shfl_xor(s, 2);
        s += __shfl_xor(s, 4);
        s += __shfl_xor(s, 8);
        const float inv = 1.0f / s;
        const int row = wave * 16 + quad * 4 + r;
#pragma unroll
        for (int ct = 0; ct < 4; ++ct)
            Ps[row * 72 + ct * 16 + l16] = (__bf16)(e[ct] * inv);
    }
    __syncthreads();

    // ---- O = P V ----
    f32x4 oacc[5] = {};
#pragma unroll
    for (int k0 = 0; k0 < 64; k0 += 32) {
        bf16x8 af = *(const bf16x8*)(Ps + (wave * 16 + l16) * 72 + k0 + quad * 8);
#pragma unroll
        for (int nt = 0; nt < 5; ++nt) {
            bf16x8 bf = *(const bf16x8*)(Vt + (nt * 16 + l16) * 72 + k0 + quad * 8);
            oacc[nt] = __builtin_amdgcn_mfma_f32_16x16x32_bf16(af, bf, oacc[nt], 0, 0, 0);
        }
    }
#pragma unroll
    for (int nt = 0; nt < 5; ++nt) {
        const int d = nt * 16 + l16;
#pragma unroll
        for (int r = 0; r < 4; ++r) {
            const int t = w * 64 + wave * 16 + quad * 4 + r;
            attn_out[(size_t)t * HID + h * HD + d] = (__bf16)oacc[nt][r];
        }
    }
}

// ---------------------------------------------------------------------------
extern "C" void kernel_launch(void* const* d_in, const int* in_sizes, int n_in,
                              void* d_out, int out_size, void* d_ws, size_t ws_size,
                              hipStream_t stream) {
    const float* x    = (const float*)d_in[0];  // [2304,1,1280]
    const float* rope = (const float*)d_in[1];  // [2304,40]
    // d_in[2] = cu_window_seqlens (statically: 36 full 64-token windows)
    const float* Wqkv = (const float*)d_in[3];  // [1280,3840]
    const float* bqkv = (const float*)d_in[4];  // [3840]
    const float* Wo   = (const float*)d_in[5];  // [1280,1280]
    const float* bo   = (const float*)d_in[6];  // [1280]
    float* out = (float*)d_out;

    // workspace layout (regionA reused after gemm_qkv):
    //   [0          , 5.90 MB) Xb      -> later attn_bf
    //   [5.90 MB    , 15.73MB) Wqkv_t  -> later Wo_t
    //   [15.73MB    , 33.42MB) qkv_bf
    char* ws = (char*)d_ws;
    const size_t szXb   = (size_t)T_TOK * HID * 2;     // 5,898,240
    const size_t szWq   = (size_t)QKV_N * HID * 2;     // 9,830,400
    __bf16* Xb      = (__bf16*)ws;
    __bf16* Wqkv_t  = (__bf16*)(ws + szXb);
    __bf16* attn_bf = (__bf16*)ws;                     // aliases Xb (dead)
    __bf16* Wo_t    = (__bf16*)(ws + szXb);            // aliases Wqkv_t (dead)
    __bf16* qkv_bf  = (__bf16*)(ws + szXb + szWq);

    // pre-passes
    convert_bf16_kernel<<<(T_TOK * HID) / (256 * 8), 256, 0, stream>>>(x, Xb);
    transpose_bf16_kernel<<<dim3(QKV_N / 64, HID / 64), 256, 0, stream>>>(Wqkv, Wqkv_t, HID, QKV_N);

    // qkv = Xb @ Wqkv + bqkv  (bf16 out)
    gemm_bt_kernel<__bf16><<<dim3(QKV_N / 128, T_TOK / 128), 256, 0, stream>>>(
        Xb, Wqkv_t, bqkv, qkv_bf, QKV_N);

    // Wo transpose (after gemm_qkv so it can alias Wqkv_t's slot)
    transpose_bf16_kernel<<<dim3(HID / 64, HID / 64), 256, 0, stream>>>(Wo, Wo_t, HID, HID);

    // attention (aliases Xb's slot — Xb dead after gemm_qkv)
    attn_win_kernel<<<dim3(NWIN, NH), 256, 0, stream>>>(qkv_bf, rope, attn_bf);

    // out = attn @ Wo + bo  (fp32 out)
    gemm_bt_kernel<float><<<dim3(HID / 128, T_TOK / 128), 256, 0, stream>>>(
        attn_bf, Wo_t, bo, out, HID);
}

// Round 3
// 171.173 us; speedup vs baseline: 1.6069x; 1.0053x over previous
//
#include <hip/hip_runtime.h>
#include <hip/hip_bf16.h>

typedef __bf16 bf16x8 __attribute__((ext_vector_type(8)));
typedef __bf16 bf16x4v __attribute__((ext_vector_type(4)));
typedef float  f32x4  __attribute__((ext_vector_type(4)));

#define T_TOK   2304
#define HID     1280
#define QKV_N   3840
#define NH      16
#define HD      80
#define NWIN    36

// ---------------------------------------------------------------------------
// async global->LDS 16B copy (wave-uniform LDS base + lane*16 semantics)
// ---------------------------------------------------------------------------
__device__ inline void async_copy16(const __bf16* g, __bf16* l) {
    __builtin_amdgcn_global_load_lds(
        (const __attribute__((address_space(1))) unsigned int*)g,
        (__attribute__((address_space(3))) unsigned int*)l, 16, 0, 0);
}

// ---------------------------------------------------------------------------
// prep: range0 converts x fp32->bf16; range1/2 transpose-convert Wqkv / Wo
// to B^T bf16 layout. Single launch, 3-range 1D grid (wave-uniform branches).
// ---------------------------------------------------------------------------
#define NB_CONV 1440   // 2304*1280 / (256*8)
#define NB_WQKV 1200   // (1280/64) * (3840/64)
#define NB_WO    400   // (1280/64) * (1280/64)

__global__ __launch_bounds__(256) void prep_kernel(
    const float* __restrict__ x,    __bf16* __restrict__ Xb,
    const float* __restrict__ Wqkv, __bf16* __restrict__ Wqkv_t,
    const float* __restrict__ Wo,   __bf16* __restrict__ Wo_t)
{
    __shared__ float t[64][65];
    int b = blockIdx.x;
    const int tid = threadIdx.x;

    if (b < NB_CONV) {
        const int i = (b * 256 + tid) * 8;
        const float4* p = (const float4*)(x + i);
        float4 a0 = p[0], a1 = p[1];
        bf16x8 o;
        o[0] = (__bf16)a0.x; o[1] = (__bf16)a0.y; o[2] = (__bf16)a0.z; o[3] = (__bf16)a0.w;
        o[4] = (__bf16)a1.x; o[5] = (__bf16)a1.y; o[6] = (__bf16)a1.z; o[7] = (__bf16)a1.w;
        *(bf16x8*)(Xb + i) = o;
        return;
    }

    const float* in; __bf16* out; int C, c0, r0;
    const int R = 1280;
    if (b < NB_CONV + NB_WQKV) {
        b -= NB_CONV;
        in = Wqkv; out = Wqkv_t; C = QKV_N;
        c0 = (b % 60) * 64; r0 = (b / 60) * 64;
    } else {
        b -= NB_CONV + NB_WQKV;
        in = Wo; out = Wo_t; C = HID;
        c0 = (b % 20) * 64; r0 = (b / 20) * 64;
    }

    const int lr = tid >> 4;           // 0..15
    const int lc = (tid & 15) * 4;     // 0..60
#pragma unroll
    for (int i = 0; i < 4; ++i) {
        float4 v = *(const float4*)(in + (size_t)(r0 + lr + i * 16) * C + c0 + lc);
        float* d = &t[lr + i * 16][lc];
        d[0] = v.x; d[1] = v.y; d[2] = v.z; d[3] = v.w;
    }
    __syncthreads();
    const int oc  = tid >> 4;
    const int orr = (tid & 15) * 4;
#pragma unroll
    for (int i = 0; i < 4; ++i) {
        const int c = oc + i * 16;
        bf16x4v o;
        o[0] = (__bf16)t[orr + 0][c];
        o[1] = (__bf16)t[orr + 1][c];
        o[2] = (__bf16)t[orr + 2][c];
        o[3] = (__bf16)t[orr + 3][c];
        *(bf16x4v*)(out + (size_t)(c0 + c) * R + r0 + orr) = o;
    }
}

// ---------------------------------------------------------------------------
// m97-style GEMM: out[M,N] = A[M,1280](bf16) @ Bt[N,1280](bf16)^T + bias.
// 128x128 tile, BK=32, global_load_lds 16B staging, 4 waves (2x2), each wave
// 64x64 = 4x4 grid of 16x16x32 MFMAs.
// ---------------------------------------------------------------------------
template<typename OutT>
__global__ __launch_bounds__(256) void gemm_bt_kernel(
    const __bf16* __restrict__ A,
    const __bf16* __restrict__ Bt,
    const float* __restrict__ bias,
    OutT* __restrict__ out,
    int N)
{
    const int n0 = blockIdx.x * 128;
    const int m0 = blockIdx.y * 128;

    __shared__ __align__(16) __bf16 As[128 * 32];
    __shared__ __align__(16) __bf16 Bs[128 * 32];

    const int tid  = threadIdx.x;
    const int wave = tid >> 6;
    const int lane = tid & 63;
    const int quad = lane >> 4;
    const int l16  = lane & 15;
    const int wm   = (wave >> 1) * 64;
    const int wn   = (wave & 1) * 64;

    const int srow = lane >> 2;
    const int scol = (lane & 3) * 8;

    f32x4 acc[4][4] = {};

    for (int k0 = 0; k0 < 1280; k0 += 32) {
        __syncthreads();
#pragma unroll
        for (int i = 0; i < 2; ++i) {
            const int r = wave * 32 + i * 16 + srow;
            async_copy16(A  + (size_t)(m0 + r) * 1280 + k0 + scol, As + r * 32 + scol);
            async_copy16(Bt + (size_t)(n0 + r) * 1280 + k0 + scol, Bs + r * 32 + scol);
        }
        __syncthreads();

        bf16x8 af[4], bf[4];
#pragma unroll
        for (int i = 0; i < 4; ++i) {
            af[i] = *(const bf16x8*)(As + (wm + i * 16 + l16) * 32 + quad * 8);
            bf[i] = *(const bf16x8*)(Bs + (wn + i * 16 + l16) * 32 + quad * 8);
        }
#pragma unroll
        for (int mt = 0; mt < 4; ++mt)
#pragma unroll
            for (int nt = 0; nt < 4; ++nt)
                acc[mt][nt] = __builtin_amdgcn_mfma_f32_16x16x32_bf16(
                    af[mt], bf[nt], acc[mt][nt], 0, 0, 0);
    }

#pragma unroll
    for (int nt = 0; nt < 4; ++nt) {
        const int col = n0 + wn + nt * 16 + l16;
        const float b = bias[col];
#pragma unroll
        for (int mt = 0; mt < 4; ++mt) {
#pragma unroll
            for (int r = 0; r < 4; ++r) {
                const int row = m0 + wm + mt * 16 + quad * 4 + r;
                out[(size_t)row * N + col] = (OutT)(acc[mt][nt][r] + b);
            }
        }
    }
}

// ---------------------------------------------------------------------------
// Fused rotary + windowed attention. One block per (window, head).
// 36 full 64-token windows -> dense 64x64 softmax blocks, no masking.
// Load phase: unit = (token t, octet-pair p). Six bf16x8 global loads,
// rotary on 8 pairs in registers, vector LDS stores; lanes run along t so
// the Vt (transposed) scatter stores are bank-conflict-free.
// ---------------------------------------------------------------------------
__global__ __launch_bounds__(256) void attn_win_kernel(
    const __bf16* __restrict__ qkv,   // [2304, 3840]
    const float* __restrict__ rope,   // [2304, 40]
    __bf16* __restrict__ attn_out)    // [2304, 1280]
{
    const int w = blockIdx.x;
    const int h = blockIdx.y;

    __shared__ __bf16 Qs[64 * 104];  // [t][d], d padded 80->96, stride 104
    __shared__ __bf16 Ks[64 * 104];
    __shared__ __bf16 Vt[80 * 72];   // [d][t], stride 72
    __shared__ __bf16 Ps[64 * 72];   // probs, stride 72

    const int tid = threadIdx.x;

    // ---- load + rotary: 320 units (64 t x 5 octet-pairs) ----
    for (int u = tid; u < 320; u += 256) {
        const int t = u & 63;         // lanes consecutive in t
        const int p = u >> 6;         // 0..4
        const int tg = w * 64 + t;
        const size_t base = (size_t)tg * QKV_N + h * HD;
        const int d0 = p * 8;

        bf16x8 qa = *(const bf16x8*)(qkv + base + d0);
        bf16x8 qb = *(const bf16x8*)(qkv + base + d0 + 40);
        bf16x8 ka = *(const bf16x8*)(qkv + base + HID + d0);
        bf16x8 kb = *(const bf16x8*)(qkv + base + HID + d0 + 40);
        bf16x8 va = *(const bf16x8*)(qkv + base + 2 * HID + d0);
        bf16x8 vb = *(const bf16x8*)(qkv + base + 2 * HID + d0 + 40);
        float4 r0 = *(const float4*)(rope + tg * 40 + d0);
        float4 r1 = *(const float4*)(rope + tg * 40 + d0 + 4);
        const float ang[8] = {r0.x, r0.y, r0.z, r0.w, r1.x, r1.y, r1.z, r1.w};

        bf16x8 qoa, qob, koa, kob;
#pragma unroll
        for (int j = 0; j < 8; ++j) {
            float sn, cs;
            __sincosf(ang[j], &sn, &cs);
            const float q0 = (float)qa[j], q1 = (float)qb[j];
            const float k0 = (float)ka[j], k1 = (float)kb[j];
            qoa[j] = (__bf16)(q0 * cs - q1 * sn);
            qob[j] = (__bf16)(q0 * sn + q1 * cs);
            koa[j] = (__bf16)(k0 * cs - k1 * sn);
            kob[j] = (__bf16)(k0 * sn + k1 * cs);
        }
        *(bf16x8*)(Qs + t * 104 + d0)      = qoa;
        *(bf16x8*)(Qs + t * 104 + d0 + 40) = qob;
        *(bf16x8*)(Ks + t * 104 + d0)      = koa;
        *(bf16x8*)(Ks + t * 104 + d0 + 40) = kob;
#pragma unroll
        for (int j = 0; j < 8; ++j) {
            Vt[(d0 + j) * 72 + t]      = va[j];
            Vt[(d0 + j + 40) * 72 + t] = vb[j];
        }
    }
    // zero-pad d in [80,96)
    for (int idx = tid; idx < 64 * 16; idx += 256) {
        const int t = idx >> 4, d = 80 + (idx & 15);
        Qs[t * 104 + d] = (__bf16)0.f;
        Ks[t * 104 + d] = (__bf16)0.f;
    }
    __syncthreads();

    const int wave = tid >> 6, lane = tid & 63;
    const int quad = lane >> 4, l16 = lane & 15;

    // ---- S = Q K^T ----
    f32x4 sacc[4] = {};
#pragma unroll
    for (int k0 = 0; k0 < 96; k0 += 32) {
        bf16x8 af = *(const bf16x8*)(Qs + (wave * 16 + l16) * 104 + k0 + quad * 8);
#pragma unroll
        for (int ct = 0; ct < 4; ++ct) {
            bf16x8 bf = *(const bf16x8*)(Ks + (ct * 16 + l16) * 104 + k0 + quad * 8);
            sacc[ct] = __builtin_amdgcn_mfma_f32_16x16x32_bf16(af, bf, sacc[ct], 0, 0, 0);
        }
    }

    // ---- in-register softmax over the 16-lane row group ----
    const float scale = 0.11180339887498948f;  // 1/sqrt(80)
#pragma unroll
    for (int r = 0; r < 4; ++r) {
        float m = -1e30f;
#pragma unroll
        for (int ct = 0; ct < 4; ++ct) {
            sacc[ct][r] *= scale;
            m = fmaxf(m, sacc[ct][r]);
        }
        m = fmaxf(m, __shfl_xor(m, 1));
        m = fmaxf(m, __shfl_xor(m, 2));
        m = fmaxf(m, __shfl_xor(m, 4));
        m = fmaxf(m, __shfl_xor(m, 8));
        float e[4], s = 0.f;
#pragma unroll
        for (int ct = 0; ct < 4; ++ct) {
            e[ct] = __expf(sacc[ct][r] - m);
            s += e[ct];
        }
        s += __shfl_xor(s, 1);
        s += __shfl_xor(s, 2);
        s += __shfl_xor(s, 4);
        s += __shfl_xor(s, 8);
        const float inv = 1.0f / s;
        const int row = wave * 16 + quad * 4 + r;
#pragma unroll
        for (int ct = 0; ct < 4; ++ct)
            Ps[row * 72 + ct * 16 + l16] = (__bf16)(e[ct] * inv);
    }
    __syncthreads();

    // ---- O = P V ----
    f32x4 oacc[5] = {};
#pragma unroll
    for (int k0 = 0; k0 < 64; k0 += 32) {
        bf16x8 af = *(const bf16x8*)(Ps + (wave * 16 + l16) * 72 + k0 + quad * 8);
#pragma unroll
        for (int nt = 0; nt < 5; ++nt) {
            bf16x8 bf = *(const bf16x8*)(Vt + (nt * 16 + l16) * 72 + k0 + quad * 8);
            oacc[nt] = __builtin_amdgcn_mfma_f32_16x16x32_bf16(af, bf, oacc[nt], 0, 0, 0);
        }
    }
#pragma unroll
    for (int nt = 0; nt < 5; ++nt) {
        const int d = nt * 16 + l16;
#pragma unroll
        for (int r = 0; r < 4; ++r) {
            const int t = w * 64 + wave * 16 + quad * 4 + r;
            attn_out[(size_t)t * HID + h * HD + d] = (__bf16)oacc[nt][r];
        }
    }
}

// ---------------------------------------------------------------------------
extern "C" void kernel_launch(void* const* d_in, const int* in_sizes, int n_in,
                              void* d_out, int out_size, void* d_ws, size_t ws_size,
                              hipStream_t stream) {
    const float* x    = (const float*)d_in[0];
    const float* rope = (const float*)d_in[1];
    // d_in[2] = cu_window_seqlens (statically: 36 full 64-token windows)
    const float* Wqkv = (const float*)d_in[3];
    const float* bqkv = (const float*)d_in[4];
    const float* Wo   = (const float*)d_in[5];
    const float* bo   = (const float*)d_in[6];
    float* out = (float*)d_out;

    // ws layout:
    //   [0       , 5.90MB ) Xb      -> later attn_bf (Xb dead after gemm_qkv)
    //   [5.90MB  , 15.73MB) Wqkv_t
    //   [15.73MB , 19.01MB) Wo_t
    //   [19.01MB , 36.70MB) qkv_bf
    char* ws = (char*)d_ws;
    const size_t szXb = (size_t)T_TOK * HID * 2;
    const size_t szWq = (size_t)QKV_N * HID * 2;
    const size_t szWo = (size_t)HID * HID * 2;
    __bf16* Xb      = (__bf16*)ws;
    __bf16* Wqkv_t  = (__bf16*)(ws + szXb);
    __bf16* Wo_t    = (__bf16*)(ws + szXb + szWq);
    __bf16* qkv_bf  = (__bf16*)(ws + szXb + szWq + szWo);
    __bf16* attn_bf = (__bf16*)ws;   // aliases Xb

    prep_kernel<<<NB_CONV + NB_WQKV + NB_WO, 256, 0, stream>>>(
        x, Xb, Wqkv, Wqkv_t, Wo, Wo_t);

    gemm_bt_kernel<__bf16><<<dim3(QKV_N / 128, T_TOK / 128), 256, 0, stream>>>(
        Xb, Wqkv_t, bqkv, qkv_bf, QKV_N);

    attn_win_kernel<<<dim3(NWIN, NH), 256, 0, stream>>>(qkv_bf, rope, attn_bf);

    gemm_bt_kernel<float><<<dim3(HID / 128, T_TOK / 128), 256, 0, stream>>>(
        attn_bf, Wo_t, bo, out, HID);
}